// Round 10
// baseline (119.568 us; speedup 1.0000x reference)
//
#include <hip/hip_runtime.h>
#include <hip/hip_bf16.h>
#include <math.h>

// VectorQuantizer: z [65536 x 64] fp32, codebook [1024 x 64] fp32.
// dist = (||z||^2 - 2 z.e) + ||e||^2, argmin_k, first-occurrence ties.
// Numeric chain identical to R4-R9 (all passed absmax 0): np pairwise sumsq
// for S/cn; d via f16 split-2 3-pass MFMA; dist=(S-2d)+cn explicit __f*_rn;
// (dist, lowest-k) lexicographic min via u64 key == f64 fmin (positive, no NaN).
//
// R9 post-mortem: VGPR_Count=64 for ~115 live regs -> 6MB/pass scratch spill
// (WRITE 23MB vs 16.7 outputs). Empirical budget law across R2-R9:
// budget ~= 256/launch_bounds_arg2, regardless of block size
// ((256,2)->128, (256,3)->84, (256,4)->64, (1024,default)->64).
// R10: __launch_bounds__(1024, 2) -> 128-VGPR budget (= the launchability
// cap for a 16-wave block anyway). Structure unchanged: 16 waves own 64
// codes each in registers; 128 z-rows -> shared A-frag tiles in LDS;
// barrier-free 8-tile main loop (5 ds_read_b128 + 24 MFMA + epilogue).
// smerge overlaid on dead zf region (zf reads complete before first write).

#define D      64
#define K      1024

typedef _Float16 half8_t __attribute__((ext_vector_type(8)));
typedef float    floatx4 __attribute__((ext_vector_type(4)));
typedef unsigned long long u64;

#define WS_CN_OFF 0          // float[1024]
#define WS_EF_OFF 4096       // _Float16[131072]: wave w's 64-code frags at
                             // half-off w*8192 + 512*((spl*2+ch)*4+ct) + 8*lane

// numpy pairwise sumsq (n=64): 8 stride-8 accs of fl(x^2), tree combine.
__device__ __forceinline__ float np_sumsq64_p(const float* __restrict__ x) {
    float r[8];
    {
        float4 v0 = *(const float4*)(x);
        float4 v1 = *(const float4*)(x + 4);
        r[0] = __fmul_rn(v0.x, v0.x); r[1] = __fmul_rn(v0.y, v0.y);
        r[2] = __fmul_rn(v0.z, v0.z); r[3] = __fmul_rn(v0.w, v0.w);
        r[4] = __fmul_rn(v1.x, v1.x); r[5] = __fmul_rn(v1.y, v1.y);
        r[6] = __fmul_rn(v1.z, v1.z); r[7] = __fmul_rn(v1.w, v1.w);
    }
#pragma unroll
    for (int i = 8; i < 64; i += 8) {
        float4 v0 = *(const float4*)(x + i);
        float4 v1 = *(const float4*)(x + i + 4);
        r[0] = __fadd_rn(r[0], __fmul_rn(v0.x, v0.x));
        r[1] = __fadd_rn(r[1], __fmul_rn(v0.y, v0.y));
        r[2] = __fadd_rn(r[2], __fmul_rn(v0.z, v0.z));
        r[3] = __fadd_rn(r[3], __fmul_rn(v0.w, v0.w));
        r[4] = __fadd_rn(r[4], __fmul_rn(v1.x, v1.x));
        r[5] = __fadd_rn(r[5], __fmul_rn(v1.y, v1.y));
        r[6] = __fadd_rn(r[6], __fmul_rn(v1.z, v1.z));
        r[7] = __fadd_rn(r[7], __fmul_rn(v1.w, v1.w));
    }
    return __fadd_rn(__fadd_rn(__fadd_rn(r[0], r[1]), __fadd_rn(r[2], r[3])),
                     __fadd_rn(__fadd_rn(r[4], r[5]), __fadd_rn(r[6], r[7])));
}

// ---- precompute: code norms + f16 split-2 B-frags (layout unchanged) ----
__global__ void vq_pre(const float* __restrict__ cb, float* __restrict__ cn,
                       _Float16* __restrict__ ef) {
    const int k = blockIdx.x * 64 + threadIdx.x;
    if (k >= K) return;
    cn[k] = np_sumsq64_p(cb + (long)k * D);
    const int t = k >> 6, ct = (k >> 4) & 3, l16 = k & 15;
#pragma unroll
    for (int ch = 0; ch < 2; ++ch)
#pragma unroll
        for (int quad = 0; quad < 4; ++quad) {
            const float* p = cb + (long)k * D + ch * 32 + quad * 8;
            half8_t h1, h2;
#pragma unroll
            for (int j = 0; j < 8; ++j) {
                float x10 = __fmul_rn(p[j], 1024.0f);        // exact pow2 scale
                _Float16 g1 = (_Float16)x10;
                h1[j] = g1;
                h2[j] = (_Float16)(__fmul_rn(__fsub_rn(x10, (float)g1), 2048.0f));
            }
            const int base = t * 8192 + 128 * quad + 8 * l16;
            *(half8_t*)(ef + base + 512 * (ch * 4 + ct))       = h1;
            *(half8_t*)(ef + base + 512 * ((2 + ch) * 4 + ct)) = h2;
        }
}

// ---- main: 1024-thr block, 128 rows; wave wv owns codes [wv*64, wv*64+64) ----
__global__ __launch_bounds__(1024, 2) void vq_main(
    const float* __restrict__ z, const float* __restrict__ cb,
    const _Float16* __restrict__ ef, const float* __restrict__ cn,
    float* __restrict__ zq, float* __restrict__ idx_out) {
    // zf (34816 B) overlaid with smerge (128*18*8 = 18432 B): zf reads all
    // complete before the first smerge write (separated by a barrier).
    __shared__ __align__(16) char uzone[128 * 68 * 4];
    __shared__ __align__(16) _Float16 za[8 * 2048];      // 8 A-frag tiles, 4KB ea
    __shared__ float sS[128];
    __shared__ int   sBi[128];
    float* zf     = (float*)uzone;
    u64*   smerge = (u64*)uzone;                         // [row][wave], pad 18

    const int tid  = threadIdx.x;
    const int lane = tid & 63;
    const int wv   = tid >> 6;       // 0..15
    const int quad = lane >> 4;
    const int l16  = lane & 15;
    const long rowbase = (long)blockIdx.x * 128;

    // ---- B-frags for my 64 codes: 16 global b128, once (L2/L3-hot) ----
    const _Float16* myef = ef + wv * 8192;
    half8_t b1[4][2], b2[4][2];
#pragma unroll
    for (int ct = 0; ct < 4; ++ct)
#pragma unroll
        for (int ch = 0; ch < 2; ++ch) {
            b1[ct][ch] = *(const half8_t*)(myef + 512 * (ch * 4 + ct) + 8 * lane);
            b2[ct][ch] = *(const half8_t*)(myef + 512 * ((2 + ch) * 4 + ct) + 8 * lane);
        }
    const int kl = wv * 64 + l16;      // key-low base; code id = kl + ct*16
    float mycn[4];
#pragma unroll
    for (int ct = 0; ct < 4; ++ct) mycn[ct] = cn[kl + ct * 16];

    // ---- stage z (coalesced): 2 float4 per thread ----
    const float4* gz = (const float4*)(z + rowbase * D);
#pragma unroll
    for (int i = 0; i < 2; ++i) {
        int idx4 = i * 1024 + tid;
        int r = idx4 >> 4, j = idx4 & 15;
        *(float4*)(zf + r * 68 + j * 4) = gz[idx4];
    }
    __syncthreads();

    // ---- row norms (exact np chain): 8 rows per wave, lanes 0..7 ----
    if (lane < 8) sS[wv * 8 + lane] = np_sumsq64_p(zf + (wv * 8 + lane) * 68);

    // ---- A-frag build, shared: wave wv builds (tile=wv>>1, spl=wv&1) ----
    {
        const int t = wv >> 1, spl = wv & 1;
#pragma unroll
        for (int ch = 0; ch < 2; ++ch) {
            const float* p = zf + (t * 16 + l16) * 68 + ch * 32 + quad * 8;
            float4 f0 = *(const float4*)(p);
            float4 f1 = *(const float4*)(p + 4);
            float xs[8] = {f0.x, f0.y, f0.z, f0.w, f1.x, f1.y, f1.z, f1.w};
            half8_t h;
#pragma unroll
            for (int j = 0; j < 8; ++j) {
                _Float16 h1 = (_Float16)xs[j];
                h[j] = spl ? (_Float16)(__fmul_rn(__fsub_rn(xs[j], (float)h1), 2048.0f))
                           : h1;
            }
            *(half8_t*)(za + t * 2048 + (spl * 2 + ch) * 512 + 8 * lane) = h;
        }
    }
    __syncthreads();   // all zf reads done; za + sS visible; smerge may be written

    const double INF_KEY = __builtin_bit_cast(double, 0x7F800000FFFFFFFFull);

    // ---- barrier-free main loop: 8 row-tiles x my 64 codes ----
    for (int t = 0; t < 8; ++t) {
        half8_t a1[2], a2[2];
#pragma unroll
        for (int ch = 0; ch < 2; ++ch) {
            a1[ch] = *(const half8_t*)(za + t * 2048 + ch * 512 + 8 * lane);
            a2[ch] = *(const half8_t*)(za + t * 2048 + (2 + ch) * 512 + 8 * lane);
        }
        float4 Sv4 = *(const float4*)(sS + t * 16 + quad * 4);
        float Sarr[4] = {Sv4.x, Sv4.y, Sv4.z, Sv4.w};
        double best[4] = {INF_KEY, INF_KEY, INF_KEY, INF_KEY};

#pragma unroll
        for (int ct = 0; ct < 4; ++ct) {
            floatx4 aM = (floatx4){0.f, 0.f, 0.f, 0.f};
            floatx4 aC = (floatx4){0.f, 0.f, 0.f, 0.f};
#pragma unroll
            for (int ch = 0; ch < 2; ++ch) {
                aM = __builtin_amdgcn_mfma_f32_16x16x32_f16(a1[ch], b1[ct][ch], aM, 0, 0, 0);
                aC = __builtin_amdgcn_mfma_f32_16x16x32_f16(a1[ch], b2[ct][ch], aC, 0, 0, 0);
                aC = __builtin_amdgcn_mfma_f32_16x16x32_f16(a2[ch], b1[ct][ch], aC, 0, 0, 0);
            }
            const unsigned kg = (unsigned)(kl + ct * 16);
#pragma unroll
            for (int r = 0; r < 4; ++r) {
                float ds = fmaf(aC[r], 0x1p-11f, aM[r]);    // 1024*d, one round
                float t2 = __fmul_rn(ds, 0x1p-9f);          // 2d, exact pow2
                float dist = __fadd_rn(__fsub_rn(Sarr[r], t2), mycn[ct]);
                uint2 u; u.x = kg; u.y = __float_as_uint(dist);
                best[r] = fmin(best[r], __builtin_bit_cast(double, u));
            }
        }
        // reduce over the 16 code-cols (within quad group); key-min is exact
#pragma unroll
        for (int r = 0; r < 4; ++r) {
            double v = best[r];
#pragma unroll
            for (int off = 1; off <= 8; off <<= 1)
                v = fmin(v, __shfl_xor(v, off));
            if (l16 == 0)
                smerge[(t * 16 + quad * 4 + r) * 18 + wv] = __builtin_bit_cast(u64, v);
        }
    }
    __syncthreads();

    // ---- final per-row reduce over 16 waves ----
    if (lane < 8) {
        const int row = wv * 8 + lane;
        const u64* m = smerge + row * 18;
        double v = __builtin_bit_cast(double, m[0]);
#pragma unroll
        for (int i = 1; i < 16; ++i)
            v = fmin(v, __builtin_bit_cast(double, m[i]));
        const unsigned kbest = (unsigned)(__builtin_bit_cast(u64, v) & 0xFFFFFFFFull);
        sBi[row] = (int)kbest;
        idx_out[rowbase + row] = (float)kbest;
    }
    __syncthreads();

    // ---- zq gather: 8 threads/row, 2 float4 each (cb L2-hot) ----
    {
        const int row = tid >> 3, j = tid & 7;
        const int kk = sBi[row];
        const float4* src = (const float4*)(cb + (long)kk * D);
        float4* dst = (float4*)(zq + (rowbase + row) * D);
        dst[j * 2]     = src[j * 2];
        dst[j * 2 + 1] = src[j * 2 + 1];
    }
}

extern "C" void kernel_launch(void* const* d_in, const int* in_sizes, int n_in,
                              void* d_out, int out_size, void* d_ws, size_t ws_size,
                              hipStream_t stream) {
    const float* z  = (const float*)d_in[0];
    const float* cb = (const float*)d_in[1];

    const int n_rows = in_sizes[0] / D;                 // 65536
    float* zq      = (float*)d_out;
    float* idx_out = zq + (long)n_rows * D;

    float*    ws_cn = (float*)((char*)d_ws + WS_CN_OFF);
    _Float16* ws_ef = (_Float16*)((char*)d_ws + WS_EF_OFF);

    vq_pre<<<K / 64, 64, 0, stream>>>(cb, ws_cn, ws_ef);
    vq_main<<<n_rows / 128, 1024, 0, stream>>>(z, cb, ws_ef, ws_cn, zq, idx_out);
}

// Round 11
// 118.861 us; speedup vs baseline: 1.0059x; 1.0059x over previous
//
#include <hip/hip_runtime.h>
#include <hip/hip_bf16.h>
#include <math.h>

// VectorQuantizer: z [65536 x 64] fp32, codebook [1024 x 64] fp32.
// dist = (||z||^2 - 2 z.e) + ||e||^2, argmin_k, first-occurrence ties.
// Numeric chain identical to R4-R10 (all passed absmax 0): np pairwise sumsq
// for S/cn; d via f16 split-2 3-pass MFMA; dist=(S-2d)+cn explicit __f*_rn;
// (dist, lowest-k) lexicographic min via u64 key == f64 fmin (positive, no NaN).
//
// R10 post-mortem: (1024,2) STILL pinned VGPR=64 (spill 33MB). Reconciled
// law: for 1024-thr blocks arg2 acts as blocks/CU -> (1024,2)=32 waves/CU
// = 8 waves/SIMD = 64 VGPRs. Fix: __launch_bounds__(1024, 1) -> 1 block/CU
// = 4 waves/SIMD = 128-VGPR budget (also the structural cap for a 16-wave
// block). ~115 live regs now fit; zero scratch. Structure unchanged from
// R9/R10: 16 waves own 64 codes each in registers (B-frags loaded once);
// 128 z-rows staged once -> shared A-frag tiles in LDS; barrier-free 8-tile
// main loop (5 ds_read_b128 + 24 MFMA + epilogue per tile).

#define D      64
#define K      1024

typedef _Float16 half8_t __attribute__((ext_vector_type(8)));
typedef float    floatx4 __attribute__((ext_vector_type(4)));
typedef unsigned long long u64;

#define WS_CN_OFF 0          // float[1024]
#define WS_EF_OFF 4096       // _Float16[131072]: wave w's 64-code frags at
                             // half-off w*8192 + 512*((spl*2+ch)*4+ct) + 8*lane

// numpy pairwise sumsq (n=64): 8 stride-8 accs of fl(x^2), tree combine.
__device__ __forceinline__ float np_sumsq64_p(const float* __restrict__ x) {
    float r[8];
    {
        float4 v0 = *(const float4*)(x);
        float4 v1 = *(const float4*)(x + 4);
        r[0] = __fmul_rn(v0.x, v0.x); r[1] = __fmul_rn(v0.y, v0.y);
        r[2] = __fmul_rn(v0.z, v0.z); r[3] = __fmul_rn(v0.w, v0.w);
        r[4] = __fmul_rn(v1.x, v1.x); r[5] = __fmul_rn(v1.y, v1.y);
        r[6] = __fmul_rn(v1.z, v1.z); r[7] = __fmul_rn(v1.w, v1.w);
    }
#pragma unroll
    for (int i = 8; i < 64; i += 8) {
        float4 v0 = *(const float4*)(x + i);
        float4 v1 = *(const float4*)(x + i + 4);
        r[0] = __fadd_rn(r[0], __fmul_rn(v0.x, v0.x));
        r[1] = __fadd_rn(r[1], __fmul_rn(v0.y, v0.y));
        r[2] = __fadd_rn(r[2], __fmul_rn(v0.z, v0.z));
        r[3] = __fadd_rn(r[3], __fmul_rn(v0.w, v0.w));
        r[4] = __fadd_rn(r[4], __fmul_rn(v1.x, v1.x));
        r[5] = __fadd_rn(r[5], __fmul_rn(v1.y, v1.y));
        r[6] = __fadd_rn(r[6], __fmul_rn(v1.z, v1.z));
        r[7] = __fadd_rn(r[7], __fmul_rn(v1.w, v1.w));
    }
    return __fadd_rn(__fadd_rn(__fadd_rn(r[0], r[1]), __fadd_rn(r[2], r[3])),
                     __fadd_rn(__fadd_rn(r[4], r[5]), __fadd_rn(r[6], r[7])));
}

// ---- precompute: code norms + f16 split-2 B-frags (layout unchanged) ----
__global__ void vq_pre(const float* __restrict__ cb, float* __restrict__ cn,
                       _Float16* __restrict__ ef) {
    const int k = blockIdx.x * 64 + threadIdx.x;
    if (k >= K) return;
    cn[k] = np_sumsq64_p(cb + (long)k * D);
    const int t = k >> 6, ct = (k >> 4) & 3, l16 = k & 15;
#pragma unroll
    for (int ch = 0; ch < 2; ++ch)
#pragma unroll
        for (int quad = 0; quad < 4; ++quad) {
            const float* p = cb + (long)k * D + ch * 32 + quad * 8;
            half8_t h1, h2;
#pragma unroll
            for (int j = 0; j < 8; ++j) {
                float x10 = __fmul_rn(p[j], 1024.0f);        // exact pow2 scale
                _Float16 g1 = (_Float16)x10;
                h1[j] = g1;
                h2[j] = (_Float16)(__fmul_rn(__fsub_rn(x10, (float)g1), 2048.0f));
            }
            const int base = t * 8192 + 128 * quad + 8 * l16;
            *(half8_t*)(ef + base + 512 * (ch * 4 + ct))       = h1;
            *(half8_t*)(ef + base + 512 * ((2 + ch) * 4 + ct)) = h2;
        }
}

// ---- main: 1024-thr block, 128 rows; wave wv owns codes [wv*64, wv*64+64) ----
__global__ __launch_bounds__(1024, 1) void vq_main(
    const float* __restrict__ z, const float* __restrict__ cb,
    const _Float16* __restrict__ ef, const float* __restrict__ cn,
    float* __restrict__ zq, float* __restrict__ idx_out) {
    // zf (34816 B) overlaid with smerge (128*18*8 = 18432 B): zf reads all
    // complete before the first smerge write (separated by a barrier).
    __shared__ __align__(16) char uzone[128 * 68 * 4];
    __shared__ __align__(16) _Float16 za[8 * 2048];      // 8 A-frag tiles, 4KB ea
    __shared__ float sS[128];
    __shared__ int   sBi[128];
    float* zf     = (float*)uzone;
    u64*   smerge = (u64*)uzone;                         // [row][wave], pad 18

    const int tid  = threadIdx.x;
    const int lane = tid & 63;
    const int wv   = tid >> 6;       // 0..15
    const int quad = lane >> 4;
    const int l16  = lane & 15;
    const long rowbase = (long)blockIdx.x * 128;

    // ---- B-frags for my 64 codes: 16 global b128, once (L2/L3-hot) ----
    const _Float16* myef = ef + wv * 8192;
    half8_t b1[4][2], b2[4][2];
#pragma unroll
    for (int ct = 0; ct < 4; ++ct)
#pragma unroll
        for (int ch = 0; ch < 2; ++ch) {
            b1[ct][ch] = *(const half8_t*)(myef + 512 * (ch * 4 + ct) + 8 * lane);
            b2[ct][ch] = *(const half8_t*)(myef + 512 * ((2 + ch) * 4 + ct) + 8 * lane);
        }
    const int kl = wv * 64 + l16;      // key-low base; code id = kl + ct*16
    float mycn[4];
#pragma unroll
    for (int ct = 0; ct < 4; ++ct) mycn[ct] = cn[kl + ct * 16];

    // ---- stage z (coalesced): 2 float4 per thread ----
    const float4* gz = (const float4*)(z + rowbase * D);
#pragma unroll
    for (int i = 0; i < 2; ++i) {
        int idx4 = i * 1024 + tid;
        int r = idx4 >> 4, j = idx4 & 15;
        *(float4*)(zf + r * 68 + j * 4) = gz[idx4];
    }
    __syncthreads();

    // ---- row norms (exact np chain): 8 rows per wave, lanes 0..7 ----
    if (lane < 8) sS[wv * 8 + lane] = np_sumsq64_p(zf + (wv * 8 + lane) * 68);

    // ---- A-frag build, shared: wave wv builds (tile=wv>>1, spl=wv&1) ----
    {
        const int t = wv >> 1, spl = wv & 1;
#pragma unroll
        for (int ch = 0; ch < 2; ++ch) {
            const float* p = zf + (t * 16 + l16) * 68 + ch * 32 + quad * 8;
            float4 f0 = *(const float4*)(p);
            float4 f1 = *(const float4*)(p + 4);
            float xs[8] = {f0.x, f0.y, f0.z, f0.w, f1.x, f1.y, f1.z, f1.w};
            half8_t h;
#pragma unroll
            for (int j = 0; j < 8; ++j) {
                _Float16 h1 = (_Float16)xs[j];
                h[j] = spl ? (_Float16)(__fmul_rn(__fsub_rn(xs[j], (float)h1), 2048.0f))
                           : h1;
            }
            *(half8_t*)(za + t * 2048 + (spl * 2 + ch) * 512 + 8 * lane) = h;
        }
    }
    __syncthreads();   // all zf reads done; za + sS visible; smerge may be written

    const double INF_KEY = __builtin_bit_cast(double, 0x7F800000FFFFFFFFull);

    // ---- barrier-free main loop: 8 row-tiles x my 64 codes ----
    for (int t = 0; t < 8; ++t) {
        half8_t a1[2], a2[2];
#pragma unroll
        for (int ch = 0; ch < 2; ++ch) {
            a1[ch] = *(const half8_t*)(za + t * 2048 + ch * 512 + 8 * lane);
            a2[ch] = *(const half8_t*)(za + t * 2048 + (2 + ch) * 512 + 8 * lane);
        }
        float4 Sv4 = *(const float4*)(sS + t * 16 + quad * 4);
        float Sarr[4] = {Sv4.x, Sv4.y, Sv4.z, Sv4.w};
        double best[4] = {INF_KEY, INF_KEY, INF_KEY, INF_KEY};

#pragma unroll
        for (int ct = 0; ct < 4; ++ct) {
            floatx4 aM = (floatx4){0.f, 0.f, 0.f, 0.f};
            floatx4 aC = (floatx4){0.f, 0.f, 0.f, 0.f};
#pragma unroll
            for (int ch = 0; ch < 2; ++ch) {
                aM = __builtin_amdgcn_mfma_f32_16x16x32_f16(a1[ch], b1[ct][ch], aM, 0, 0, 0);
                aC = __builtin_amdgcn_mfma_f32_16x16x32_f16(a1[ch], b2[ct][ch], aC, 0, 0, 0);
                aC = __builtin_amdgcn_mfma_f32_16x16x32_f16(a2[ch], b1[ct][ch], aC, 0, 0, 0);
            }
            const unsigned kg = (unsigned)(kl + ct * 16);
#pragma unroll
            for (int r = 0; r < 4; ++r) {
                float ds = fmaf(aC[r], 0x1p-11f, aM[r]);    // 1024*d, one round
                float t2 = __fmul_rn(ds, 0x1p-9f);          // 2d, exact pow2
                float dist = __fadd_rn(__fsub_rn(Sarr[r], t2), mycn[ct]);
                uint2 u; u.x = kg; u.y = __float_as_uint(dist);
                best[r] = fmin(best[r], __builtin_bit_cast(double, u));
            }
        }
        // reduce over the 16 code-cols (within quad group); key-min is exact
#pragma unroll
        for (int r = 0; r < 4; ++r) {
            double v = best[r];
#pragma unroll
            for (int off = 1; off <= 8; off <<= 1)
                v = fmin(v, __shfl_xor(v, off));
            if (l16 == 0)
                smerge[(t * 16 + quad * 4 + r) * 18 + wv] = __builtin_bit_cast(u64, v);
        }
    }
    __syncthreads();

    // ---- final per-row reduce over 16 waves ----
    if (lane < 8) {
        const int row = wv * 8 + lane;
        const u64* m = smerge + row * 18;
        double v = __builtin_bit_cast(double, m[0]);
#pragma unroll
        for (int i = 1; i < 16; ++i)
            v = fmin(v, __builtin_bit_cast(double, m[i]));
        const unsigned kbest = (unsigned)(__builtin_bit_cast(u64, v) & 0xFFFFFFFFull);
        sBi[row] = (int)kbest;
        idx_out[rowbase + row] = (float)kbest;
    }
    __syncthreads();

    // ---- zq gather: 8 threads/row, 2 float4 each (cb L2-hot) ----
    {
        const int row = tid >> 3, j = tid & 7;
        const int kk = sBi[row];
        const float4* src = (const float4*)(cb + (long)kk * D);
        float4* dst = (float4*)(zq + (rowbase + row) * D);
        dst[j * 2]     = src[j * 2];
        dst[j * 2 + 1] = src[j * 2 + 1];
    }
}

extern "C" void kernel_launch(void* const* d_in, const int* in_sizes, int n_in,
                              void* d_out, int out_size, void* d_ws, size_t ws_size,
                              hipStream_t stream) {
    const float* z  = (const float*)d_in[0];
    const float* cb = (const float*)d_in[1];

    const int n_rows = in_sizes[0] / D;                 // 65536
    float* zq      = (float*)d_out;
    float* idx_out = zq + (long)n_rows * D;

    float*    ws_cn = (float*)((char*)d_ws + WS_CN_OFF);
    _Float16* ws_ef = (_Float16*)((char*)d_ws + WS_EF_OFF);

    vq_pre<<<K / 64, 64, 0, stream>>>(cb, ws_cn, ws_ef);
    vq_main<<<n_rows / 128, 1024, 0, stream>>>(z, cb, ws_ef, ws_cn, zq, idx_out);
}

// Round 12
// 107.838 us; speedup vs baseline: 1.1088x; 1.1022x over previous
//
#include <hip/hip_runtime.h>
#include <hip/hip_bf16.h>
#include <math.h>

// VectorQuantizer: z [65536 x 64] fp32, codebook [1024 x 64] fp32.
// dist = (||z||^2 - 2 z.e) + ||e||^2, argmin_k, first-occurrence ties.
// Numeric chain identical to R4-R11 (all passed absmax 0): np pairwise sumsq
// for S/cn; d via f16 split-2 3-pass MFMA; dist=(S-2d)+cn explicit __f*_rn;
// (dist, lowest-k) lexicographic min via u64 key == f64 fmin (positive, no NaN).
//
// R11 post-mortem: 1024-thr MFMA kernels are PINNED at 64 arch VGPRs by the
// compiler (3 rounds of evidence, any launch_bounds) -> permanent spill.
// Only proven >=128-VGPR config: 256 thr + __launch_bounds__(256,2)
// (R3: 128 no spill, R8: 80 no spill). R12 reshapes R9's design to fit:
// 256-thr block x 32 rows, ALL 1024 codes via 4-chunk loop (B-frags
// reloaded per chunk from ef, coalesced b128, L2-hot, hidden behind ~1450cyc
// chunk compute). Per-lane best keys in regs across ALL codes -> the
// 16-lane b64 shuffle-reduce runs once per (tile,row) (8/wave), not per
// chunk. A-frags re-read from LDS per (c,t) (32 b128/wave). ~118 live regs.
// No K-split -> no memset/atomics/resolve; outputs written in-kernel.

#define D      64
#define K      1024
#define BLOCK  256

typedef _Float16 half8_t __attribute__((ext_vector_type(8)));
typedef float    floatx4 __attribute__((ext_vector_type(4)));
typedef unsigned long long u64;

#define WS_CN_OFF 0          // float[1024]
#define WS_EF_OFF 4096       // _Float16[131072]: 64-code group g's frags at
                             // half-off g*8192 + 512*((spl*2+ch)*4+ct) + 8*lane

// numpy pairwise sumsq (n=64): 8 stride-8 accs of fl(x^2), tree combine.
__device__ __forceinline__ float np_sumsq64_p(const float* __restrict__ x) {
    float r[8];
    {
        float4 v0 = *(const float4*)(x);
        float4 v1 = *(const float4*)(x + 4);
        r[0] = __fmul_rn(v0.x, v0.x); r[1] = __fmul_rn(v0.y, v0.y);
        r[2] = __fmul_rn(v0.z, v0.z); r[3] = __fmul_rn(v0.w, v0.w);
        r[4] = __fmul_rn(v1.x, v1.x); r[5] = __fmul_rn(v1.y, v1.y);
        r[6] = __fmul_rn(v1.z, v1.z); r[7] = __fmul_rn(v1.w, v1.w);
    }
#pragma unroll
    for (int i = 8; i < 64; i += 8) {
        float4 v0 = *(const float4*)(x + i);
        float4 v1 = *(const float4*)(x + i + 4);
        r[0] = __fadd_rn(r[0], __fmul_rn(v0.x, v0.x));
        r[1] = __fadd_rn(r[1], __fmul_rn(v0.y, v0.y));
        r[2] = __fadd_rn(r[2], __fmul_rn(v0.z, v0.z));
        r[3] = __fadd_rn(r[3], __fmul_rn(v0.w, v0.w));
        r[4] = __fadd_rn(r[4], __fmul_rn(v1.x, v1.x));
        r[5] = __fadd_rn(r[5], __fmul_rn(v1.y, v1.y));
        r[6] = __fadd_rn(r[6], __fmul_rn(v1.z, v1.z));
        r[7] = __fadd_rn(r[7], __fmul_rn(v1.w, v1.w));
    }
    return __fadd_rn(__fadd_rn(__fadd_rn(r[0], r[1]), __fadd_rn(r[2], r[3])),
                     __fadd_rn(__fadd_rn(r[4], r[5]), __fadd_rn(r[6], r[7])));
}

// ---- precompute: code norms + f16 split-2 B-frags (layout unchanged) ----
__global__ void vq_pre(const float* __restrict__ cb, float* __restrict__ cn,
                       _Float16* __restrict__ ef) {
    const int k = blockIdx.x * 64 + threadIdx.x;
    if (k >= K) return;
    cn[k] = np_sumsq64_p(cb + (long)k * D);
    const int t = k >> 6, ct = (k >> 4) & 3, l16 = k & 15;
#pragma unroll
    for (int ch = 0; ch < 2; ++ch)
#pragma unroll
        for (int quad = 0; quad < 4; ++quad) {
            const float* p = cb + (long)k * D + ch * 32 + quad * 8;
            half8_t h1, h2;
#pragma unroll
            for (int j = 0; j < 8; ++j) {
                float x10 = __fmul_rn(p[j], 1024.0f);        // exact pow2 scale
                _Float16 g1 = (_Float16)x10;
                h1[j] = g1;
                h2[j] = (_Float16)(__fmul_rn(__fsub_rn(x10, (float)g1), 2048.0f));
            }
            const int base = t * 8192 + 128 * quad + 8 * l16;
            *(half8_t*)(ef + base + 512 * (ch * 4 + ct))       = h1;
            *(half8_t*)(ef + base + 512 * ((2 + ch) * 4 + ct)) = h2;
        }
}

// ---- main: 256-thr block, 32 rows x ALL 1024 codes (4 chunks) ----
__global__ __launch_bounds__(BLOCK, 2) void vq_main(
    const float* __restrict__ z, const float* __restrict__ cb,
    const _Float16* __restrict__ ef, const float* __restrict__ cn,
    float* __restrict__ zq, float* __restrict__ idx_out) {
    __shared__ __align__(16) float    zf[32 * 68];       // 8704 B
    __shared__ __align__(16) _Float16 za[2 * 2048];      // 2 A-frag tiles, 8 KB
    __shared__ float sS[32];
    __shared__ u64   smerge[32 * 4];                     // [row][wave]
    __shared__ int   sBi[32];

    const int tid  = threadIdx.x;
    const int lane = tid & 63;
    const int wv   = tid >> 6;       // 0..3
    const int quad = lane >> 4;
    const int l16  = lane & 15;
    const long rowbase = (long)blockIdx.x * 32;

    // ---- stage z (coalesced): 2 float4 per thread ----
    const float4* gz = (const float4*)(z + rowbase * D);
#pragma unroll
    for (int i = 0; i < 2; ++i) {
        int idx4 = i * BLOCK + tid;
        int r = idx4 >> 4, j = idx4 & 15;
        *(float4*)(zf + r * 68 + j * 4) = gz[idx4];
    }
    __syncthreads();

    // ---- row norms (exact np chain): 32 rows, one per thread ----
    if (tid < 32) sS[tid] = np_sumsq64_p(zf + tid * 68);

    // ---- A-frag build: wave wv builds (tile=wv>>1, spl=wv&1) ----
    {
        const int t = wv >> 1, spl = wv & 1;
#pragma unroll
        for (int ch = 0; ch < 2; ++ch) {
            const float* p = zf + (t * 16 + l16) * 68 + ch * 32 + quad * 8;
            float4 f0 = *(const float4*)(p);
            float4 f1 = *(const float4*)(p + 4);
            float xs[8] = {f0.x, f0.y, f0.z, f0.w, f1.x, f1.y, f1.z, f1.w};
            half8_t h;
#pragma unroll
            for (int j = 0; j < 8; ++j) {
                _Float16 h1 = (_Float16)xs[j];
                h[j] = spl ? (_Float16)(__fmul_rn(__fsub_rn(xs[j], (float)h1), 2048.0f))
                           : h1;
            }
            *(half8_t*)(za + t * 2048 + (spl * 2 + ch) * 512 + 8 * lane) = h;
        }
    }
    __syncthreads();   // za + sS visible; no further barriers until merge

    float Sv[2][4];
#pragma unroll
    for (int t = 0; t < 2; ++t) {
        float4 s4 = *(const float4*)(sS + t * 16 + quad * 4);
        Sv[t][0] = s4.x; Sv[t][1] = s4.y; Sv[t][2] = s4.z; Sv[t][3] = s4.w;
    }

    const double INF_KEY = __builtin_bit_cast(double, 0x7F800000FFFFFFFFull);
    double best[2][4];
#pragma unroll
    for (int t = 0; t < 2; ++t)
#pragma unroll
        for (int r = 0; r < 4; ++r) best[t][r] = INF_KEY;

    // ---- chunk loop: all 1024 codes, barrier-free ----
    for (int c = 0; c < 4; ++c) {
        // B-frags for my 64 codes this chunk (coalesced b128, L2-hot)
        const _Float16* tb = ef + (c * 4 + wv) * 8192 + 8 * lane;
        half8_t b1[4][2], b2[4][2];
#pragma unroll
        for (int ct = 0; ct < 4; ++ct)
#pragma unroll
            for (int ch = 0; ch < 2; ++ch) {
                b1[ct][ch] = *(const half8_t*)(tb + 512 * (ch * 4 + ct));
                b2[ct][ch] = *(const half8_t*)(tb + 512 * ((2 + ch) * 4 + ct));
            }
        const int kb = c * 256 + wv * 64 + l16;
        float mycn[4];
#pragma unroll
        for (int ct = 0; ct < 4; ++ct) mycn[ct] = cn[kb + ct * 16];

#pragma unroll
        for (int t = 0; t < 2; ++t) {
            half8_t a1[2], a2[2];
#pragma unroll
            for (int ch = 0; ch < 2; ++ch) {
                a1[ch] = *(const half8_t*)(za + t * 2048 + ch * 512 + 8 * lane);
                a2[ch] = *(const half8_t*)(za + t * 2048 + (2 + ch) * 512 + 8 * lane);
            }
#pragma unroll
            for (int ct = 0; ct < 4; ++ct) {
                floatx4 aM = (floatx4){0.f, 0.f, 0.f, 0.f};
                floatx4 aC = (floatx4){0.f, 0.f, 0.f, 0.f};
#pragma unroll
                for (int ch = 0; ch < 2; ++ch) {
                    aM = __builtin_amdgcn_mfma_f32_16x16x32_f16(a1[ch], b1[ct][ch], aM, 0, 0, 0);
                    aC = __builtin_amdgcn_mfma_f32_16x16x32_f16(a1[ch], b2[ct][ch], aC, 0, 0, 0);
                    aC = __builtin_amdgcn_mfma_f32_16x16x32_f16(a2[ch], b1[ct][ch], aC, 0, 0, 0);
                }
                const unsigned kg = (unsigned)(kb + ct * 16);
                // C layout: col=l16 (code), row=quad*4+r
#pragma unroll
                for (int r = 0; r < 4; ++r) {
                    float ds = fmaf(aC[r], 0x1p-11f, aM[r]);   // 1024*d
                    float t2 = __fmul_rn(ds, 0x1p-9f);         // 2d, exact pow2
                    float dist = __fadd_rn(__fsub_rn(Sv[t][r], t2), mycn[ct]);
                    uint2 u; u.x = kg; u.y = __float_as_uint(dist);
                    best[t][r] = fmin(best[t][r], __builtin_bit_cast(double, u));
                }
            }
        }
    }

    // ---- ONE 16-lane reduce per (tile,row); lane0-of-group writes smerge ----
#pragma unroll
    for (int t = 0; t < 2; ++t)
#pragma unroll
        for (int r = 0; r < 4; ++r) {
            double v = best[t][r];
#pragma unroll
            for (int off = 1; off <= 8; off <<= 1)
                v = fmin(v, __shfl_xor(v, off));
            if (l16 == 0)
                smerge[(t * 16 + quad * 4 + r) * 4 + wv] = __builtin_bit_cast(u64, v);
        }
    __syncthreads();

    // ---- final per-row reduce over 4 waves ----
    if (tid < 32) {
        const u64* m = smerge + tid * 4;
        double v = __builtin_bit_cast(double, m[0]);
#pragma unroll
        for (int i = 1; i < 4; ++i)
            v = fmin(v, __builtin_bit_cast(double, m[i]));
        const unsigned kbest = (unsigned)(__builtin_bit_cast(u64, v) & 0xFFFFFFFFull);
        sBi[tid] = (int)kbest;
        idx_out[rowbase + tid] = (float)kbest;
    }
    __syncthreads();

    // ---- zq gather: 512 float4 / 256 threads (cb L2-hot) ----
    const float4* cb4 = (const float4*)cb;
    float4* zq4 = (float4*)(zq + rowbase * D);
#pragma unroll
    for (int i = 0; i < 2; ++i) {
        int idx4 = i * BLOCK + tid;
        int r = idx4 >> 4, j = idx4 & 15;
        zq4[idx4] = cb4[(long)sBi[r] * 16 + j];
    }
}

extern "C" void kernel_launch(void* const* d_in, const int* in_sizes, int n_in,
                              void* d_out, int out_size, void* d_ws, size_t ws_size,
                              hipStream_t stream) {
    const float* z  = (const float*)d_in[0];
    const float* cb = (const float*)d_in[1];

    const int n_rows = in_sizes[0] / D;                 // 65536
    float* zq      = (float*)d_out;
    float* idx_out = zq + (long)n_rows * D;

    float*    ws_cn = (float*)((char*)d_ws + WS_CN_OFF);
    _Float16* ws_ef = (_Float16*)((char*)d_ws + WS_EF_OFF);

    vq_pre<<<K / 64, 64, 0, stream>>>(cb, ws_cn, ws_ef);
    vq_main<<<n_rows / 32, BLOCK, 0, stream>>>(z, cb, ws_ef, ws_cn, zq, idx_out);
}